// Round 15
// baseline (17.958 us; speedup 1.0000x reference)
//
#include <hip/hip_runtime.h>

#define BS 1024
#define D_IN 512
#define D_OUT 512
#define N_MASKS 8
#define CB 16

typedef short bf16x8 __attribute__((ext_vector_type(8)));
typedef float f32x4 __attribute__((ext_vector_type(4)));

// ws layout: int wsi[0..8] offsets; wsi[16+p] row perm; xb (bf16 1024x512) at byte 8192
#define XB_OFF_USH (8192 / 2)

__device__ __forceinline__ ushort f2bf(float f) {
    union { float f; unsigned u; } x; x.f = f;
    unsigned r = (x.u + 0x7fffu + ((x.u >> 16) & 1u)) >> 16;  // RNE
    return (ushort)r;
}

// ---------------- Kernel 1: x->bf16 + counting sort ----------------
__global__ void __launch_bounds__(256) prep_kernel(
    const float* __restrict__ x, const int* __restrict__ state,
    int* __restrict__ wsi, ushort* __restrict__ xb)
{
    const int bx  = blockIdx.x;
    const int tid = threadIdx.x;
    if (bx < 256) {
        const int idx = bx * 256 + tid;                // [0, 65536)
        const float4 a = ((const float4*)x)[idx * 2];
        const float4 b = ((const float4*)x)[idx * 2 + 1];
        uint4 o;
        o.x = (uint)f2bf(a.x) | ((uint)f2bf(a.y) << 16);
        o.y = (uint)f2bf(a.z) | ((uint)f2bf(a.w) << 16);
        o.z = (uint)f2bf(b.x) | ((uint)f2bf(b.y) << 16);
        o.w = (uint)f2bf(b.z) | ((uint)f2bf(b.w) << 16);
        *(uint4*)(xb + (size_t)idx * 8) = o;
    } else {
        __shared__ int cnt[N_MASKS];
        __shared__ int offs[N_MASKS + 1];
        if (tid < N_MASKS) cnt[tid] = 0;
        __syncthreads();
        int s[4];
        #pragma unroll
        for (int r = 0; r < 4; ++r) {
            s[r] = state[r * 256 + tid];
            atomicAdd(&cnt[s[r]], 1);
        }
        __syncthreads();
        if (tid == 0) {
            int acc = 0;
            for (int i = 0; i < N_MASKS; ++i) { offs[i] = acc; acc += cnt[i]; }
            offs[N_MASKS] = acc;
        }
        __syncthreads();
        if (tid <= N_MASKS) wsi[tid] = offs[tid];
        if (tid < N_MASKS) cnt[tid] = offs[tid];   // scatter cursors
        __syncthreads();
        #pragma unroll
        for (int r = 0; r < 4; ++r) {
            const int pos = atomicAdd(&cnt[s[r]], 1);
            wsi[16 + pos] = r * 256 + tid;
        }
    }
}

// ---------------- Fused GEMM v15: LDS-resident W, bf16 A, 4 waves/SIMD ----------------
// grid = (mask n fastest -> XCD n, 32 col-tiles of 16, 2 row-halves) = 512 blocks
// x 512 thr = 2 blocks/CU (stagger staging vs compute), 16 waves/CU = 4/SIMD.
// LDS wlds (r2/r13-verified fragment layout): slot(kbg, lane=(g,cl)) = kbg*64+g*16+cl,
// 8 ushorts: B[k=kbg*32+g*8+j][c0+cl], j=0..7.
__global__ void __launch_bounds__(512, 2) gemm_kernel(
    const ushort* __restrict__ xb, const float* __restrict__ kern,
    const float* __restrict__ masks, const int* __restrict__ wsi,
    float* __restrict__ out)
{
    __shared__ ushort wlds[16 * 64 * 8];   // 16 KB
    __shared__ float red[4][64][4];        // 4 KB

    const int n   = blockIdx.x;
    const int c0  = blockIdx.y * CB;
    const int z   = blockIdx.z;
    const int tid = threadIdx.x;
    const float* __restrict__ maskn = masks + (size_t)n * (D_IN * D_OUT);

    // ---- stage kern*mask (512 x 16 cols) -> LDS fragments; 2 passes ----
    // thread: k-pair p = it*128 + (tid>>2), col4 q = tid&3
    #pragma unroll
    for (int it = 0; it < 2; ++it) {
        const int p = it * 128 + (tid >> 2);   // k-pair [0,256)
        const int q = tid & 3;
        const size_t gidx = (size_t)(2 * p) * D_OUT + c0 + q * 4;
        const float4 k0 = *(const float4*)&kern[gidx];
        const float4 k1 = *(const float4*)&kern[gidx + D_OUT];
        const float4 m0 = *(const float4*)&maskn[gidx];
        const float4 m1 = *(const float4*)&maskn[gidx + D_OUT];
        const int kb = p >> 4, gg = (p >> 2) & 3, h = p & 3;
        const float w0[4] = {k0.x*m0.x, k0.y*m0.y, k0.z*m0.z, k0.w*m0.w};
        const float w1[4] = {k1.x*m1.x, k1.y*m1.y, k1.z*m1.z, k1.w*m1.w};
        #pragma unroll
        for (int j = 0; j < 4; ++j) {
            const int c = q * 4 + j;           // local col 0..15
            const int slot = kb * 64 + gg * 16 + c;
            ((uint*)wlds)[slot * 4 + h] =
                (uint)f2bf(w0[j]) | ((uint)f2bf(w1[j]) << 16);
        }
    }

    const int off0 = wsi[n], off1 = wsi[n + 1];
    const int gcnt = off1 - off0;
    const int T = (gcnt + 15) >> 4;     // rowtiles in group
    const int M = (T + 7) >> 3;         // uniform trips (usually 1)

    const int lane = tid & 63;
    const int wid  = tid >> 6;
    const int rtl  = wid >> 1;          // rowtile slot 0..3
    const int kh   = wid & 1;           // K-half
    const int g    = lane >> 4;
    const int cl   = lane & 15;

    __syncthreads();

    for (int m = 0; m < M; ++m) {
        const int rt = z * 4 + rtl + 8 * m;
        const bool active = (rt < T);
        f32x4 acc = {0.f, 0.f, 0.f, 0.f};
        int rv = -1;
        if (active) {
            const int p = off0 + rt * 16 + cl;
            rv = (p < off1) ? wsi[16 + p] : -1;
            const ushort* xr = xb + (size_t)(rv < 0 ? 0 : rv) * D_IN + kh * 256 + g * 8;
            #pragma unroll
            for (int i = 0; i < 8; ++i) {      // kbg = kh*8 + i
                const bf16x8 a = *(const bf16x8*)(xr + i * 32);
                const bf16x8 b = *(const bf16x8*)&wlds[(((kh * 8 + i) * 64) + lane) * 8];
                acc = __builtin_amdgcn_mfma_f32_16x16x32_bf16(a, b, acc, 0, 0, 0);
            }
        }
        if (kh) {
            *(f32x4*)&red[rtl][lane][0] = acc;
        }
        __syncthreads();
        if (!kh && active) {
            acc += *(const f32x4*)&red[rtl][lane][0];
            // C/D: col = cl, row-in-tile = g*4 + r
            #pragma unroll
            for (int r = 0; r < 4; ++r) {
                const int brow = __shfl(rv, g * 4 + r);
                if (brow >= 0) {
                    out[(size_t)brow * D_OUT + c0 + cl] = fmaxf(acc[r], 0.f);
                }
            }
        }
        __syncthreads();   // protect red before next trip
    }
}

extern "C" void kernel_launch(void* const* d_in, const int* in_sizes, int n_in,
                              void* d_out, int out_size, void* d_ws, size_t ws_size,
                              hipStream_t stream) {
    const float* x     = (const float*)d_in[0];
    const int*   state = (const int*)d_in[1];
    const float* kern  = (const float*)d_in[2];
    const float* masks = (const float*)d_in[3];
    float*  out = (float*)d_out;
    int*    wsi = (int*)d_ws;
    ushort* wsu = (ushort*)d_ws;

    prep_kernel<<<257, 256, 0, stream>>>(x, state, wsi, wsu + XB_OFF_USH);
    dim3 grid(N_MASKS, D_OUT / CB, 2);
    gemm_kernel<<<grid, 512, 0, stream>>>(wsu + XB_OFF_USH, kern, masks, wsi, out);
}